// Round 4
// baseline (601.717 us; speedup 1.0000x reference)
//
#include <hip/hip_runtime.h>
#include <stdint.h>

typedef __attribute__((ext_vector_type(8))) short bf16x8;   // 8 bf16 in 4 VGPRs
typedef __attribute__((ext_vector_type(4))) float f32x4;

__device__ __forceinline__ float b2f(uint32_t h) {
    union { uint32_t u; float f; } v; v.u = h << 16; return v.f;
}
__device__ __forceinline__ ushort f2b(float f) {
    union { float f; uint32_t u; } v; v.f = f;
    uint32_t u = v.u;
    return (ushort)((u + 0x7fffu + ((u >> 16) & 1u)) >> 16);
}
__device__ __forceinline__ float ldin(const void* p, int i, int fp32) {
    return fp32 ? ((const float*)p)[i] : b2f(((const ushort*)p)[i]);
}

// ---------------- dtype sniffer (64 lanes) ----------------
__global__ void k_flags(const void* W1, const void* ei, int* flags) {
    int l = threadIdx.x;
    const ushort* w = (const ushort*)W1;   // W1 ~ U(-1/16,1/16) if true bf16
    float a0 = fabsf(b2f(w[l]));
    float a1 = fabsf(b2f(w[64 + l]));
    bool bad = !(a0 <= 0.25f) || !(a1 <= 0.25f);
    unsigned long long mb = __ballot(bad);
    const int* e = (const int*)ei;         // int64: odd (high) words are 0
    bool z = (l < 16) ? (e[2 * l + 1] == 0) : false;
    unsigned long long mz = __ballot(z);
    if (l == 0) {
        flags[0] = mb ? 1 : 0;                                // fp32 floats?
        flags[1] = (__popcll(mz & 0xffffull) >= 15) ? 1 : 0;  // int64 indices?
    }
}

// ---------------- indices -> clamped int32 (+ fused degree count on dst half) ----------------
__global__ __launch_bounds__(256) void k_cvt_idx(const void* ei, const void* ep, const void* en,
                                                 int* cEi, int* cEp, int* cEn, int* __restrict__ deg,
                                                 int twoE, int twoEp, int twoEn, int N,
                                                 const int* __restrict__ flags) {
    int i = blockIdx.x * 256 + threadIdx.x;
    int i64 = flags[1];
    const void* srcp; int* dstp; int j = i; bool isdst = false;
    if (i < twoE) { srcp = ei; dstp = cEi; isdst = (i >= (twoE >> 1)); }
    else if (i < twoE + twoEp) { srcp = ep; dstp = cEp; j = i - twoE; }
    else if (i < twoE + twoEp + twoEn) { srcp = en; dstp = cEn; j = i - twoE - twoEp; }
    else return;
    int v = i64 ? (int)((const long long*)srcp)[j] : ((const int*)srcp)[j];
    v = v < 0 ? 0 : (v >= N ? N - 1 : v);
    dstp[j] = v;
    if (isdst) atomicAdd(&deg[v], 1);
}

// ---------------- weights (transpose) + biases -> bf16 ----------------
__global__ __launch_bounds__(256) void k_cvt_w(const void* W1, const void* W2, const void* Wc,
                                               const void* b1, const void* b2, const void* bc,
                                               const void* Wl, const void* bl,
                                               ushort* Wt1, ushort* Wt2, ushort* WtC,
                                               ushort* b1c, ushort* b2c, ushort* bcc,
                                               ushort* Wlc, ushort* blc,
                                               const int* __restrict__ flags) {
    int i = blockIdx.x * 256 + threadIdx.x;
    int f = flags[0];
    if (i < 32768) {
        int c = i >> 8, k = i & 255;
        Wt1[i] = f2b(ldin(W1, k * 128 + c, f));
    } else if (i < 49152) {
        int j = i - 32768, c = j >> 7, k = j & 127;
        Wt2[j] = f2b(ldin(W2, k * 128 + c, f));
    } else if (i < 51200) {
        int j = i - 49152, c = j >> 7, k = j & 127;
        ushort v = 0;
        if (c < 10) v = f2b(ldin(Wc, k * 10 + c, f));
        WtC[j] = v;
    } else if (i < 51328) {
        int j = i - 51200; b1c[j] = f2b(ldin(b1, j, f));
    } else if (i < 51456) {
        int j = i - 51328; b2c[j] = f2b(ldin(b2, j, f));
    } else if (i < 51472) {
        int j = i - 51456;
        ushort v = 0;
        if (j < 10) v = f2b(ldin(bc, j, f));
        bcc[j] = v;
    } else if (i < 51728) {
        int j = i - 51472; Wlc[j] = f2b(ldin(Wl, j, f));
    } else if (i < 51736) {
        int j = i - 51728;
        ushort v = 0;
        if (j < 1) v = f2b(ldin(bl, 0, f));
        blc[j] = v;
    }
}

// ---------------- CSR scan ----------------
__global__ __launch_bounds__(1024) void k_scan_block(const int* __restrict__ deg, int* __restrict__ rowptr,
                                                     float* __restrict__ dinv, int* __restrict__ bsum, int n) {
    __shared__ int sh[1024];
    int t = threadIdx.x;
    int i = blockIdx.x * 1024 + t;
    int val = (i < n) ? deg[i] : 0;
    sh[t] = val; __syncthreads();
    for (int off = 1; off < 1024; off <<= 1) {
        int v = (t >= off) ? sh[t - off] : 0;
        __syncthreads();
        sh[t] += v;
        __syncthreads();
    }
    if (i < n) {
        rowptr[i] = sh[t] - val;
        dinv[i] = rsqrtf((float)(val + 1));
    }
    if (t == 1023) bsum[blockIdx.x] = sh[1023];
}

__global__ __launch_bounds__(128) void k_scan_top(const int* __restrict__ bsum, int* __restrict__ boff, int nb) {
    __shared__ int sh[128];
    int t = threadIdx.x;
    int val = (t < nb) ? bsum[t] : 0;
    sh[t] = val; __syncthreads();
    for (int off = 1; off < 128; off <<= 1) {
        int v = (t >= off) ? sh[t - off] : 0;
        __syncthreads();
        sh[t] += v;
        __syncthreads();
    }
    if (t < nb) boff[t] = sh[t] - val;
}

__global__ __launch_bounds__(1024) void k_scan_add(int* __restrict__ rowptr, const int* __restrict__ boff,
                                                   int n, int E) {
    int i = blockIdx.x * 1024 + threadIdx.x;
    if (i < n) rowptr[i] += boff[blockIdx.x];
    if (i == 0) rowptr[n] = E;
}

// ---------------- CSR fill: edge = {src, dinv[src]*dinv[dst]} ----------------
__global__ __launch_bounds__(256) void k_fill(const int* __restrict__ src, const int* __restrict__ dst,
                                              const int* __restrict__ rowptr, int* __restrict__ cursor,
                                              int2* __restrict__ edge, const float* __restrict__ dinv, int E) {
    int i = blockIdx.x * 256 + threadIdx.x;
    if (i < E) {
        int d = dst[i];
        int s = src[i];
        int p = rowptr[d] + atomicAdd(&cursor[d], 1);
        float w = dinv[s] * dinv[d];
        edge[p] = make_int2(s, __float_as_int(w));
    }
}

// ---------------- MFMA GEMM: Out[N,128] = X[N,K] @ W[K,128] ----------------
// B (Wt, bf16) staged once per block into LDS in fragment order [s][n][lane]*16B
// (ds_read_b128 at lane*16+imm: conflict-free). Each wave streams 2 M-tiles per
// iteration: 32 rows of A issue as one back-to-back load burst -> deep MLP.
template <int K, bool MAYBE_F32>
__global__ __launch_bounds__(256, 2) void k_gemm(const void* __restrict__ X,
                                                 const int* __restrict__ flags,
                                                 const ushort* __restrict__ Wt,
                                                 ushort* __restrict__ Out, int nrows) {
    constexpr int NS = K / 32;            // K-steps
    __shared__ uint4 sB[NS * 8 * 64];     // K=256: 64 KB, K=128: 32 KB

    const int tid = threadIdx.x;
    // ---- stage B into LDS (fragment order) ----
    for (int it = tid; it < NS * 8 * 64; it += 256) {
        int l = it & 63, fn = it >> 6;
        int s = fn >> 3, n = fn & 7;
        int mr = l & 15, q = l >> 4;
        sB[it] = *(const uint4*)(Wt + (size_t)(n * 16 + mr) * K + s * 32 + q * 8);
    }
    __syncthreads();

    const int wave = tid >> 6;
    const int l = tid & 63;
    const int q = l >> 4, mr = l & 15;
    const int gw = blockIdx.x * 4 + wave;
    const int nw = gridDim.x * 4;
    const int ntile = (nrows + 15) >> 4;
    const bool f32in = MAYBE_F32 && flags[0];

    for (int tp = gw; tp * 2 < ntile; tp += nw) {
        const int t0 = tp * 2;
        const bool has1 = (t0 + 1 < ntile);
        const int t1 = has1 ? t0 + 1 : t0;
        const int r0 = min(t0 * 16 + mr, nrows - 1);
        const int r1 = min(t1 * 16 + mr, nrows - 1);

        bf16x8 a0[NS], a1[NS];
        if (f32in) {
            const float* x0 = (const float*)X + (size_t)r0 * K + q * 8;
            const float* x1 = (const float*)X + (size_t)r1 * K + q * 8;
            float4 ra[NS][2], rb[NS][2];
#pragma unroll
            for (int s = 0; s < NS; ++s) {
                ra[s][0] = *(const float4*)(x0 + s * 32);
                ra[s][1] = *(const float4*)(x0 + s * 32 + 4);
            }
#pragma unroll
            for (int s = 0; s < NS; ++s) {
                rb[s][0] = *(const float4*)(x1 + s * 32);
                rb[s][1] = *(const float4*)(x1 + s * 32 + 4);
            }
#pragma unroll
            for (int s = 0; s < NS; ++s) {
                a0[s][0] = (short)f2b(ra[s][0].x); a0[s][1] = (short)f2b(ra[s][0].y);
                a0[s][2] = (short)f2b(ra[s][0].z); a0[s][3] = (short)f2b(ra[s][0].w);
                a0[s][4] = (short)f2b(ra[s][1].x); a0[s][5] = (short)f2b(ra[s][1].y);
                a0[s][6] = (short)f2b(ra[s][1].z); a0[s][7] = (short)f2b(ra[s][1].w);
                a1[s][0] = (short)f2b(rb[s][0].x); a1[s][1] = (short)f2b(rb[s][0].y);
                a1[s][2] = (short)f2b(rb[s][0].z); a1[s][3] = (short)f2b(rb[s][0].w);
                a1[s][4] = (short)f2b(rb[s][1].x); a1[s][5] = (short)f2b(rb[s][1].y);
                a1[s][6] = (short)f2b(rb[s][1].z); a1[s][7] = (short)f2b(rb[s][1].w);
            }
        } else {
            const ushort* x0 = (const ushort*)X + (size_t)r0 * K + q * 8;
            const ushort* x1 = (const ushort*)X + (size_t)r1 * K + q * 8;
#pragma unroll
            for (int s = 0; s < NS; ++s) a0[s] = *(const bf16x8*)(x0 + s * 32);
#pragma unroll
            for (int s = 0; s < NS; ++s) a1[s] = *(const bf16x8*)(x1 + s * 32);
        }

        f32x4 acc0[8], acc1[8];
#pragma unroll
        for (int n = 0; n < 8; ++n) {
            acc0[n] = (f32x4){0.f, 0.f, 0.f, 0.f};
            acc1[n] = (f32x4){0.f, 0.f, 0.f, 0.f};
        }
#pragma unroll
        for (int s = 0; s < NS; ++s) {
#pragma unroll
            for (int n = 0; n < 8; ++n) {
                bf16x8 b = __builtin_bit_cast(bf16x8, sB[(s * 8 + n) * 64 + l]);
                acc0[n] = __builtin_amdgcn_mfma_f32_16x16x32_bf16(a0[s], b, acc0[n], 0, 0, 0);
                acc1[n] = __builtin_amdgcn_mfma_f32_16x16x32_bf16(a1[s], b, acc1[n], 0, 0, 0);
            }
        }
        // C/D: col = lane&15, row = q*4 + r
#pragma unroll
        for (int n = 0; n < 8; ++n) {
#pragma unroll
            for (int r = 0; r < 4; ++r) {
                int row0 = t0 * 16 + q * 4 + r;
                if (row0 < nrows) Out[(size_t)row0 * 128 + n * 16 + mr] = f2b(acc0[n][r]);
                if (has1) {
                    int row1 = t1 * 16 + q * 4 + r;
                    if (row1 < nrows) Out[(size_t)row1 * 128 + n * 16 + mr] = f2b(acc1[n][r]);
                }
            }
        }
    }
}

// ---------------- GCN aggregate: one wave per dst node, 8 edges in flight ----------------
__global__ __launch_bounds__(256) void k_conv(const ushort* __restrict__ XW, const int* __restrict__ rowptr,
                                              const int2* __restrict__ edge, const float* __restrict__ dinv,
                                              const ushort* __restrict__ bias, ushort* __restrict__ Hout,
                                              int n, int relu) {
    int wave = threadIdx.x >> 6;
    int v = blockIdx.x * 4 + wave;
    if (v >= n) return;
    int l = threadIdx.x & 63;

    int s0 = rowptr[v], s1 = rowptr[v + 1];
    float dv = dinv[v];
    uint32_t pv = *(const uint32_t*)(XW + (size_t)v * 128 + 2 * l);
    float wself = dv * dv;
    float acc0 = b2f(pv & 0xffffu) * wself;
    float acc1 = b2f(pv >> 16) * wself;

    int i = s0;
    while (i + 8 <= s1) {
        int2 e0[8];
#pragma unroll
        for (int j = 0; j < 8; ++j) e0[j] = edge[i + j];
        uint32_t p[8];
#pragma unroll
        for (int j = 0; j < 8; ++j)
            p[j] = *(const uint32_t*)(XW + (size_t)e0[j].x * 128 + 2 * l);
#pragma unroll
        for (int j = 0; j < 8; ++j) {
            float w = __int_as_float(e0[j].y);
            acc0 += b2f(p[j] & 0xffffu) * w;
            acc1 += b2f(p[j] >> 16) * w;
        }
        i += 8;
    }
    if (i < s1) {   // single predicated batch for the tail (<8)
        int2 e0[8];
#pragma unroll
        for (int j = 0; j < 8; ++j) e0[j] = edge[(i + j < s1) ? (i + j) : s0];
        uint32_t p[8];
#pragma unroll
        for (int j = 0; j < 8; ++j)
            p[j] = *(const uint32_t*)(XW + (size_t)e0[j].x * 128 + 2 * l);
#pragma unroll
        for (int j = 0; j < 8; ++j) {
            float w = (i + j < s1) ? __int_as_float(e0[j].y) : 0.f;
            acc0 += b2f(p[j] & 0xffffu) * w;
            acc1 += b2f(p[j] >> 16) * w;
        }
    }

    uint32_t bb = *(const uint32_t*)(bias + 2 * l);
    acc0 += b2f(bb & 0xffffu);
    acc1 += b2f(bb >> 16);
    if (relu) { acc0 = fmaxf(acc0, 0.f); acc1 = fmaxf(acc1, 0.f); }

    uint32_t o = (uint32_t)f2b(acc0) | ((uint32_t)f2b(acc1) << 16);
    *(uint32_t*)(Hout + (size_t)v * 128 + 2 * l) = o;
}

// ---------------- node head ----------------
__global__ __launch_bounds__(256) void k_nodehead(const ushort* __restrict__ H, const ushort* __restrict__ WtC,
                                                  const ushort* __restrict__ bcc, void* __restrict__ out,
                                                  int n, const int* __restrict__ flags) {
    int wave = threadIdx.x >> 6;
    int gw = blockIdx.x * 4 + wave;
    if (gw * 16 >= n) return;
    int fp32o = flags[0];
    int l = threadIdx.x & 63;
    int q = l >> 4, mr = l & 15;
    int m0 = gw * 16;

    f32x4 acc = (f32x4){0.f, 0.f, 0.f, 0.f};
    const ushort* hrow = H + (size_t)(m0 + mr) * 128 + q * 8;
#pragma unroll
    for (int s = 0; s < 4; ++s) {
        bf16x8 a = *(const bf16x8*)(hrow + s * 32);
#pragma unroll
        for (int j = 0; j < 8; ++j) {
            ushort t = (ushort)a[j];
            if (t & 0x8000u) a[j] = 0;   // relu on bf16
        }
        bf16x8 b = *(const bf16x8*)(WtC + (size_t)mr * 128 + s * 32 + q * 8);
        acc = __builtin_amdgcn_mfma_f32_16x16x32_bf16(a, b, acc, 0, 0, 0);
    }

    float bc = b2f(bcc[mr]);
#pragma unroll
    for (int r = 0; r < 4; ++r) {
        float logit = acc[r] + bc;
        float m = (mr < 10) ? logit : -1e30f;
#pragma unroll
        for (int off = 1; off < 16; off <<= 1) m = fmaxf(m, __shfl_xor(m, off, 16));
        float ex = (mr < 10) ? expf(logit - m) : 0.f;
        float ssum = ex;
#pragma unroll
        for (int off = 1; off < 16; off <<= 1) ssum += __shfl_xor(ssum, off, 16);
        if (mr < 10) {
            float lsm = logit - m - logf(ssum);
            size_t idx = (size_t)(m0 + q * 4 + r) * 10 + mr;
            if (fp32o) ((float*)out)[idx] = lsm;
            else ((ushort*)out)[idx] = f2b(lsm);
        }
    }
}

// ---------------- link head: 4 edges per wave, 16 lanes x dwordx4 per row ----------------
__global__ __launch_bounds__(256) void k_link(const ushort* __restrict__ H, const int* __restrict__ pos,
                                              const int* __restrict__ neg, const ushort* __restrict__ Wlc,
                                              const ushort* __restrict__ blc, void* __restrict__ out,
                                              size_t obase, int Ep, int En, const int* __restrict__ flags) {
    int wave = threadIdx.x >> 6;
    int l = threadIdx.x & 63;
    int g = l >> 4, t = l & 15;
    int e = (blockIdx.x * 4 + wave) * 4 + g;
    if (e >= Ep + En) return;
    int fp32o = flags[0];

    const int* P; int eb, off2;
    if (e < Ep) { P = pos; eb = e; off2 = Ep; }
    else { P = neg; eb = e - Ep; off2 = En; }
    int sI = P[eb], dI = P[off2 + eb];

    bf16x8 hs = *(const bf16x8*)(H + (size_t)sI * 128 + t * 8);
    bf16x8 hd = *(const bf16x8*)(H + (size_t)dI * 128 + t * 8);
    bf16x8 w0 = *(const bf16x8*)(Wlc + t * 8);
    bf16x8 w1 = *(const bf16x8*)(Wlc + 128 + t * 8);

    float acc = 0.f;
#pragma unroll
    for (int j = 0; j < 8; ++j) {
        acc += b2f((ushort)hs[j]) * b2f((ushort)w0[j]);
        acc += b2f((ushort)hd[j]) * b2f((ushort)w1[j]);
    }
#pragma unroll
    for (int off = 1; off < 16; off <<= 1) acc += __shfl_xor(acc, off, 16);
    if (t == 0) {
        float vf = acc + b2f(blc[0]);
        size_t idx = obase + (size_t)e;
        if (fp32o) ((float*)out)[idx] = vf;
        else ((ushort*)out)[idx] = f2b(vf);
    }
}

extern "C" void kernel_launch(void* const* d_in, const int* in_sizes, int n_in,
                              void* d_out, int out_size, void* d_ws, size_t ws_size,
                              hipStream_t stream) {
    const void* x    = d_in[0];
    const void* ei   = d_in[1];
    const void* eip  = d_in[2];
    const void* ein  = d_in[3];
    const void* W1   = d_in[4];
    const void* b1   = d_in[5];
    const void* W2   = d_in[6];
    const void* b2   = d_in[7];
    const void* Wcls = d_in[8];
    const void* bcls = d_in[9];
    const void* Wl   = d_in[10];
    const void* bl   = d_in[11];

    const int N  = in_sizes[0] / 256;
    const int E  = in_sizes[1] / 2;
    const int Ep = in_sizes[2] / 2;
    const int En = in_sizes[3] / 2;

    char* ws = (char*)d_ws;
    size_t off = 0;
    auto alloc = [&](size_t bytes) -> void* {
        void* p = ws + off;
        off = (off + bytes + 255) & ~(size_t)255;
        return p;
    };
    int*    flags = (int*)alloc(256);
    ushort* bufXW = (ushort*)alloc((size_t)N * 128 * 2);
    ushort* bufH  = (ushort*)alloc((size_t)N * 128 * 2);
    int*    cEi   = (int*)alloc((size_t)2 * E * 4);
    int*    cEp   = (int*)alloc((size_t)2 * Ep * 4);
    int*    cEn   = (int*)alloc((size_t)2 * En * 4);
    float*  dinv  = (float*)alloc((size_t)N * 4);
    int*    deg   = (int*)alloc((size_t)N * 4);
    int*    cur   = (int*)alloc((size_t)N * 4);
    int*    rowp  = (int*)alloc((size_t)(N + 1) * 4);
    int2*   edge  = (int2*)alloc((size_t)E * 8);
    int*    bsum  = (int*)alloc(1024);
    int*    boff  = (int*)alloc(1024);
    ushort* Wt1   = (ushort*)alloc(65536);
    ushort* Wt2   = (ushort*)alloc(32768);
    ushort* WtC   = (ushort*)alloc(4096);
    ushort* b1c   = (ushort*)alloc(256);
    ushort* b2c   = (ushort*)alloc(256);
    ushort* bcc   = (ushort*)alloc(64);
    ushort* Wlc   = (ushort*)alloc(512);
    ushort* blc   = (ushort*)alloc(64);

    hipMemsetAsync(deg, 0, (size_t)N * 4, stream);
    hipMemsetAsync(cur, 0, (size_t)N * 4, stream);

    k_flags<<<1, 64, 0, stream>>>(W1, ei, flags);

    int twoE = 2 * E, twoEp = 2 * Ep, twoEn = 2 * En;
    int idx_total = twoE + twoEp + twoEn;
    k_cvt_idx<<<(idx_total + 255) / 256, 256, 0, stream>>>(ei, eip, ein, cEi, cEp, cEn, deg,
                                                           twoE, twoEp, twoEn, N, flags);
    k_cvt_w<<<203, 256, 0, stream>>>(W1, W2, Wcls, b1, b2, bcls, Wl, bl,
                                     Wt1, Wt2, WtC, b1c, b2c, bcc, Wlc, blc, flags);

    const int* srcp = cEi;
    const int* dstp = cEi + E;
    int nb = (N + 1023) / 1024;
    k_scan_block<<<nb, 1024, 0, stream>>>(deg, rowp, dinv, bsum, N);
    k_scan_top<<<1, 128, 0, stream>>>(bsum, boff, nb);
    k_scan_add<<<nb, 1024, 0, stream>>>(rowp, boff, N, E);
    k_fill<<<(E + 255) / 256, 256, 0, stream>>>(srcp, dstp, rowp, cur, edge, dinv, E);

    k_gemm<256, true><<<512, 256, 0, stream>>>(x, flags, Wt1, bufXW, N);
    k_conv<<<(N + 3) / 4, 256, 0, stream>>>(bufXW, rowp, edge, dinv, b1c, bufH, N, 1);
    k_gemm<128, false><<<768, 256, 0, stream>>>(bufH, flags, Wt2, bufXW, N);
    k_conv<<<(N + 3) / 4, 256, 0, stream>>>(bufXW, rowp, edge, dinv, b2c, bufH, N, 0);

    int head_blocks = ((N + 15) / 16 + 3) / 4;
    k_nodehead<<<head_blocks, 256, 0, stream>>>(bufH, WtC, bcc, d_out, N, flags);
    k_link<<<(Ep + En + 3) / 4, 256, 0, stream>>>(bufH, cEp, cEn, Wlc, blc, d_out,
                                                  (size_t)N * 10, Ep, En, flags);
}

// Round 5
// 598.505 us; speedup vs baseline: 1.0054x; 1.0054x over previous
//
#include <hip/hip_runtime.h>
#include <stdint.h>

typedef __attribute__((ext_vector_type(8))) short bf16x8;   // 8 bf16 in 4 VGPRs
typedef __attribute__((ext_vector_type(4))) float f32x4;

__device__ __forceinline__ float b2f(uint32_t h) {
    union { uint32_t u; float f; } v; v.u = h << 16; return v.f;
}
__device__ __forceinline__ ushort f2b(float f) {
    union { float f; uint32_t u; } v; v.f = f;
    uint32_t u = v.u;
    return (ushort)((u + 0x7fffu + ((u >> 16) & 1u)) >> 16);
}
__device__ __forceinline__ float ldin(const void* p, int i, int fp32) {
    return fp32 ? ((const float*)p)[i] : b2f(((const ushort*)p)[i]);
}

// ---------------- dtype sniffer (64 lanes) ----------------
__global__ void k_flags(const void* W1, const void* ei, int* flags) {
    int l = threadIdx.x;
    const ushort* w = (const ushort*)W1;   // W1 ~ U(-1/16,1/16) if true bf16
    float a0 = fabsf(b2f(w[l]));
    float a1 = fabsf(b2f(w[64 + l]));
    bool bad = !(a0 <= 0.25f) || !(a1 <= 0.25f);
    unsigned long long mb = __ballot(bad);
    const int* e = (const int*)ei;         // int64: odd (high) words are 0
    bool z = (l < 16) ? (e[2 * l + 1] == 0) : false;
    unsigned long long mz = __ballot(z);
    if (l == 0) {
        flags[0] = mb ? 1 : 0;                                // fp32 floats?
        flags[1] = (__popcll(mz & 0xffffull) >= 15) ? 1 : 0;  // int64 indices?
    }
}

// ---------------- indices -> clamped int32 (+ fused degree count on dst half) ----------------
__global__ __launch_bounds__(256) void k_cvt_idx(const void* ei, const void* ep, const void* en,
                                                 int* cEi, int* cEp, int* cEn, int* __restrict__ deg,
                                                 int twoE, int twoEp, int twoEn, int N,
                                                 const int* __restrict__ flags) {
    int i = blockIdx.x * 256 + threadIdx.x;
    int i64 = flags[1];
    const void* srcp; int* dstp; int j = i; bool isdst = false;
    if (i < twoE) { srcp = ei; dstp = cEi; isdst = (i >= (twoE >> 1)); }
    else if (i < twoE + twoEp) { srcp = ep; dstp = cEp; j = i - twoE; }
    else if (i < twoE + twoEp + twoEn) { srcp = en; dstp = cEn; j = i - twoE - twoEp; }
    else return;
    int v = i64 ? (int)((const long long*)srcp)[j] : ((const int*)srcp)[j];
    v = v < 0 ? 0 : (v >= N ? N - 1 : v);
    dstp[j] = v;
    if (isdst) atomicAdd(&deg[v], 1);
}

// ---------------- weights (transpose) + biases -> bf16 ----------------
__global__ __launch_bounds__(256) void k_cvt_w(const void* W1, const void* W2, const void* Wc,
                                               const void* b1, const void* b2, const void* bc,
                                               const void* Wl, const void* bl,
                                               ushort* Wt1, ushort* Wt2, ushort* WtC,
                                               ushort* b1c, ushort* b2c, ushort* bcc,
                                               ushort* Wlc, ushort* blc,
                                               const int* __restrict__ flags) {
    int i = blockIdx.x * 256 + threadIdx.x;
    int f = flags[0];
    if (i < 32768) {
        int c = i >> 8, k = i & 255;
        Wt1[i] = f2b(ldin(W1, k * 128 + c, f));
    } else if (i < 49152) {
        int j = i - 32768, c = j >> 7, k = j & 127;
        Wt2[j] = f2b(ldin(W2, k * 128 + c, f));
    } else if (i < 51200) {
        int j = i - 49152, c = j >> 7, k = j & 127;
        ushort v = 0;
        if (c < 10) v = f2b(ldin(Wc, k * 10 + c, f));
        WtC[j] = v;
    } else if (i < 51328) {
        int j = i - 51200; b1c[j] = f2b(ldin(b1, j, f));
    } else if (i < 51456) {
        int j = i - 51328; b2c[j] = f2b(ldin(b2, j, f));
    } else if (i < 51472) {
        int j = i - 51456;
        ushort v = 0;
        if (j < 10) v = f2b(ldin(bc, j, f));
        bcc[j] = v;
    } else if (i < 51728) {
        int j = i - 51472; Wlc[j] = f2b(ldin(Wl, j, f));
    } else if (i < 51736) {
        int j = i - 51728;
        ushort v = 0;
        if (j < 1) v = f2b(ldin(bl, 0, f));
        blc[j] = v;
    }
}

// ---------------- x fp32 -> bf16 (streaming, only when fp32) ----------------
__global__ __launch_bounds__(256) void k_cvt_x(const void* __restrict__ x, ushort* __restrict__ xc,
                                               int total, const int* __restrict__ flags) {
    if (!flags[0]) return;
    int i = (blockIdx.x * 256 + threadIdx.x) * 8;
    if (i >= total) return;
    const float* xf = (const float*)x;
    float4 a = *(const float4*)(xf + i);
    float4 b = *(const float4*)(xf + i + 4);
    uint4 o;
    o.x = (uint32_t)f2b(a.x) | ((uint32_t)f2b(a.y) << 16);
    o.y = (uint32_t)f2b(a.z) | ((uint32_t)f2b(a.w) << 16);
    o.z = (uint32_t)f2b(b.x) | ((uint32_t)f2b(b.y) << 16);
    o.w = (uint32_t)f2b(b.z) | ((uint32_t)f2b(b.w) << 16);
    *(uint4*)(xc + i) = o;
}

// ---------------- CSR scan ----------------
__global__ __launch_bounds__(1024) void k_scan_block(const int* __restrict__ deg, int* __restrict__ rowptr,
                                                     float* __restrict__ dinv, int* __restrict__ bsum, int n) {
    __shared__ int sh[1024];
    int t = threadIdx.x;
    int i = blockIdx.x * 1024 + t;
    int val = (i < n) ? deg[i] : 0;
    sh[t] = val; __syncthreads();
    for (int off = 1; off < 1024; off <<= 1) {
        int v = (t >= off) ? sh[t - off] : 0;
        __syncthreads();
        sh[t] += v;
        __syncthreads();
    }
    if (i < n) {
        rowptr[i] = sh[t] - val;
        dinv[i] = rsqrtf((float)(val + 1));
    }
    if (t == 1023) bsum[blockIdx.x] = sh[1023];
}

__global__ __launch_bounds__(128) void k_scan_top(const int* __restrict__ bsum, int* __restrict__ boff, int nb) {
    __shared__ int sh[128];
    int t = threadIdx.x;
    int val = (t < nb) ? bsum[t] : 0;
    sh[t] = val; __syncthreads();
    for (int off = 1; off < 128; off <<= 1) {
        int v = (t >= off) ? sh[t - off] : 0;
        __syncthreads();
        sh[t] += v;
        __syncthreads();
    }
    if (t < nb) boff[t] = sh[t] - val;
}

__global__ __launch_bounds__(1024) void k_scan_add(int* __restrict__ rowptr, const int* __restrict__ boff,
                                                   int n, int E) {
    int i = blockIdx.x * 1024 + threadIdx.x;
    if (i < n) rowptr[i] += boff[blockIdx.x];
    if (i == 0) rowptr[n] = E;
}

// ---------------- CSR fill: edge = {src, dinv[src]*dinv[dst]} ----------------
__global__ __launch_bounds__(256) void k_fill(const int* __restrict__ src, const int* __restrict__ dst,
                                              const int* __restrict__ rowptr, int* __restrict__ cursor,
                                              int2* __restrict__ edge, const float* __restrict__ dinv, int E) {
    int i = blockIdx.x * 256 + threadIdx.x;
    if (i < E) {
        int d = dst[i];
        int s = src[i];
        int p = rowptr[d] + atomicAdd(&cursor[d], 1);
        float w = dinv[s] * dinv[d];
        edge[p] = make_int2(s, __float_as_int(w));
    }
}

// ---------------- MFMA GEMM (bf16 A): Out[N,128] = X[N,K] @ W[K,128] ----------------
// B staged once per block into LDS in fragment order (ds_read_b128 conflict-free).
// 2 M-tiles per wave-iteration: 16 A-loads issue back-to-back -> deep MLP, no spill.
template <int K, bool SEL>
__global__ __launch_bounds__(256, 2) void k_gemm(const void* __restrict__ Xraw,
                                                 const ushort* __restrict__ Xc,
                                                 const int* __restrict__ flags,
                                                 const ushort* __restrict__ Wt,
                                                 ushort* __restrict__ Out, int nrows) {
    constexpr int NS = K / 32;            // K-steps
    __shared__ uint4 sB[NS * 8 * 64];     // K=256: 64 KB, K=128: 32 KB

    const int tid = threadIdx.x;
    for (int it = tid; it < NS * 8 * 64; it += 256) {
        int l = it & 63, fn = it >> 6;
        int s = fn >> 3, n = fn & 7;
        int mr = l & 15, q = l >> 4;
        sB[it] = *(const uint4*)(Wt + (size_t)(n * 16 + mr) * K + s * 32 + q * 8);
    }
    __syncthreads();

    const ushort* Xp = SEL ? (flags[0] ? Xc : (const ushort*)Xraw) : (const ushort*)Xraw;
    const int wave = tid >> 6;
    const int l = tid & 63;
    const int q = l >> 4, mr = l & 15;
    const int gw = blockIdx.x * 4 + wave;
    const int nw = gridDim.x * 4;
    const int ntile = (nrows + 15) >> 4;

    for (int tp = gw; tp * 2 < ntile; tp += nw) {
        const int t0 = tp * 2;
        const bool has1 = (t0 + 1 < ntile);
        const int t1 = has1 ? t0 + 1 : t0;
        const int r0 = min(t0 * 16 + mr, nrows - 1);
        const int r1 = min(t1 * 16 + mr, nrows - 1);

        bf16x8 a0[NS], a1[NS];
        const ushort* x0 = Xp + (size_t)r0 * K + q * 8;
        const ushort* x1 = Xp + (size_t)r1 * K + q * 8;
#pragma unroll
        for (int s = 0; s < NS; ++s) a0[s] = *(const bf16x8*)(x0 + s * 32);
#pragma unroll
        for (int s = 0; s < NS; ++s) a1[s] = *(const bf16x8*)(x1 + s * 32);

        f32x4 acc0[8], acc1[8];
#pragma unroll
        for (int n = 0; n < 8; ++n) {
            acc0[n] = (f32x4){0.f, 0.f, 0.f, 0.f};
            acc1[n] = (f32x4){0.f, 0.f, 0.f, 0.f};
        }
#pragma unroll
        for (int s = 0; s < NS; ++s) {
#pragma unroll
            for (int n = 0; n < 8; ++n) {
                bf16x8 b = __builtin_bit_cast(bf16x8, sB[(s * 8 + n) * 64 + l]);
                acc0[n] = __builtin_amdgcn_mfma_f32_16x16x32_bf16(a0[s], b, acc0[n], 0, 0, 0);
                acc1[n] = __builtin_amdgcn_mfma_f32_16x16x32_bf16(a1[s], b, acc1[n], 0, 0, 0);
            }
        }
        // C/D: col = lane&15, row = q*4 + r
#pragma unroll
        for (int n = 0; n < 8; ++n) {
#pragma unroll
            for (int r = 0; r < 4; ++r) {
                int row0 = t0 * 16 + q * 4 + r;
                if (row0 < nrows) Out[(size_t)row0 * 128 + n * 16 + mr] = f2b(acc0[n][r]);
                if (has1) {
                    int row1 = t1 * 16 + q * 4 + r;
                    if (row1 < nrows) Out[(size_t)row1 * 128 + n * 16 + mr] = f2b(acc1[n][r]);
                }
            }
        }
    }
}

// ---------------- GCN aggregate: one wave per dst node, 8 edges in flight ----------------
__global__ __launch_bounds__(256) void k_conv(const ushort* __restrict__ XW, const int* __restrict__ rowptr,
                                              const int2* __restrict__ edge, const float* __restrict__ dinv,
                                              const ushort* __restrict__ bias, ushort* __restrict__ Hout,
                                              int n, int relu) {
    int wave = threadIdx.x >> 6;
    int v = blockIdx.x * 4 + wave;
    if (v >= n) return;
    int l = threadIdx.x & 63;

    int s0 = rowptr[v], s1 = rowptr[v + 1];
    float dv = dinv[v];
    uint32_t pv = *(const uint32_t*)(XW + (size_t)v * 128 + 2 * l);
    float wself = dv * dv;
    float acc0 = b2f(pv & 0xffffu) * wself;
    float acc1 = b2f(pv >> 16) * wself;

    int i = s0;
    while (i + 8 <= s1) {
        int2 e0[8];
#pragma unroll
        for (int j = 0; j < 8; ++j) e0[j] = edge[i + j];
        uint32_t p[8];
#pragma unroll
        for (int j = 0; j < 8; ++j)
            p[j] = *(const uint32_t*)(XW + (size_t)e0[j].x * 128 + 2 * l);
#pragma unroll
        for (int j = 0; j < 8; ++j) {
            float w = __int_as_float(e0[j].y);
            acc0 += b2f(p[j] & 0xffffu) * w;
            acc1 += b2f(p[j] >> 16) * w;
        }
        i += 8;
    }
    if (i < s1) {   // single predicated batch for the tail (<8)
        int2 e0[8];
#pragma unroll
        for (int j = 0; j < 8; ++j) e0[j] = edge[(i + j < s1) ? (i + j) : s0];
        uint32_t p[8];
#pragma unroll
        for (int j = 0; j < 8; ++j)
            p[j] = *(const uint32_t*)(XW + (size_t)e0[j].x * 128 + 2 * l);
#pragma unroll
        for (int j = 0; j < 8; ++j) {
            float w = (i + j < s1) ? __int_as_float(e0[j].y) : 0.f;
            acc0 += b2f(p[j] & 0xffffu) * w;
            acc1 += b2f(p[j] >> 16) * w;
        }
    }

    uint32_t bb = *(const uint32_t*)(bias + 2 * l);
    acc0 += b2f(bb & 0xffffu);
    acc1 += b2f(bb >> 16);
    if (relu) { acc0 = fmaxf(acc0, 0.f); acc1 = fmaxf(acc1, 0.f); }

    uint32_t o = (uint32_t)f2b(acc0) | ((uint32_t)f2b(acc1) << 16);
    *(uint32_t*)(Hout + (size_t)v * 128 + 2 * l) = o;
}

// ---------------- node head ----------------
__global__ __launch_bounds__(256) void k_nodehead(const ushort* __restrict__ H, const ushort* __restrict__ WtC,
                                                  const ushort* __restrict__ bcc, void* __restrict__ out,
                                                  int n, const int* __restrict__ flags) {
    int wave = threadIdx.x >> 6;
    int gw = blockIdx.x * 4 + wave;
    if (gw * 16 >= n) return;
    int fp32o = flags[0];
    int l = threadIdx.x & 63;
    int q = l >> 4, mr = l & 15;
    int m0 = gw * 16;

    f32x4 acc = (f32x4){0.f, 0.f, 0.f, 0.f};
    const ushort* hrow = H + (size_t)(m0 + mr) * 128 + q * 8;
#pragma unroll
    for (int s = 0; s < 4; ++s) {
        bf16x8 a = *(const bf16x8*)(hrow + s * 32);
#pragma unroll
        for (int j = 0; j < 8; ++j) {
            ushort t = (ushort)a[j];
            if (t & 0x8000u) a[j] = 0;   // relu on bf16
        }
        bf16x8 b = *(const bf16x8*)(WtC + (size_t)mr * 128 + s * 32 + q * 8);
        acc = __builtin_amdgcn_mfma_f32_16x16x32_bf16(a, b, acc, 0, 0, 0);
    }

    float bc = b2f(bcc[mr]);
#pragma unroll
    for (int r = 0; r < 4; ++r) {
        float logit = acc[r] + bc;
        float m = (mr < 10) ? logit : -1e30f;
#pragma unroll
        for (int off = 1; off < 16; off <<= 1) m = fmaxf(m, __shfl_xor(m, off, 16));
        float ex = (mr < 10) ? expf(logit - m) : 0.f;
        float ssum = ex;
#pragma unroll
        for (int off = 1; off < 16; off <<= 1) ssum += __shfl_xor(ssum, off, 16);
        if (mr < 10) {
            float lsm = logit - m - logf(ssum);
            size_t idx = (size_t)(m0 + q * 4 + r) * 10 + mr;
            if (fp32o) ((float*)out)[idx] = lsm;
            else ((ushort*)out)[idx] = f2b(lsm);
        }
    }
}

// ---------------- link head: 4 edges per wave, 16 lanes x dwordx4 per row ----------------
__global__ __launch_bounds__(256) void k_link(const ushort* __restrict__ H, const int* __restrict__ pos,
                                              const int* __restrict__ neg, const ushort* __restrict__ Wlc,
                                              const ushort* __restrict__ blc, void* __restrict__ out,
                                              size_t obase, int Ep, int En, const int* __restrict__ flags) {
    int wave = threadIdx.x >> 6;
    int l = threadIdx.x & 63;
    int g = l >> 4, t = l & 15;
    int e = (blockIdx.x * 4 + wave) * 4 + g;
    if (e >= Ep + En) return;
    int fp32o = flags[0];

    const int* P; int eb, off2;
    if (e < Ep) { P = pos; eb = e; off2 = Ep; }
    else { P = neg; eb = e - Ep; off2 = En; }
    int sI = P[eb], dI = P[off2 + eb];

    bf16x8 hs = *(const bf16x8*)(H + (size_t)sI * 128 + t * 8);
    bf16x8 hd = *(const bf16x8*)(H + (size_t)dI * 128 + t * 8);
    bf16x8 w0 = *(const bf16x8*)(Wlc + t * 8);
    bf16x8 w1 = *(const bf16x8*)(Wlc + 128 + t * 8);

    float acc = 0.f;
#pragma unroll
    for (int j = 0; j < 8; ++j) {
        acc += b2f((ushort)hs[j]) * b2f((ushort)w0[j]);
        acc += b2f((ushort)hd[j]) * b2f((ushort)w1[j]);
    }
#pragma unroll
    for (int off = 1; off < 16; off <<= 1) acc += __shfl_xor(acc, off, 16);
    if (t == 0) {
        float vf = acc + b2f(blc[0]);
        size_t idx = obase + (size_t)e;
        if (fp32o) ((float*)out)[idx] = vf;
        else ((ushort*)out)[idx] = f2b(vf);
    }
}

extern "C" void kernel_launch(void* const* d_in, const int* in_sizes, int n_in,
                              void* d_out, int out_size, void* d_ws, size_t ws_size,
                              hipStream_t stream) {
    const void* x    = d_in[0];
    const void* ei   = d_in[1];
    const void* eip  = d_in[2];
    const void* ein  = d_in[3];
    const void* W1   = d_in[4];
    const void* b1   = d_in[5];
    const void* W2   = d_in[6];
    const void* b2   = d_in[7];
    const void* Wcls = d_in[8];
    const void* bcls = d_in[9];
    const void* Wl   = d_in[10];
    const void* bl   = d_in[11];

    const int N  = in_sizes[0] / 256;
    const int E  = in_sizes[1] / 2;
    const int Ep = in_sizes[2] / 2;
    const int En = in_sizes[3] / 2;

    char* ws = (char*)d_ws;
    size_t off = 0;
    auto alloc = [&](size_t bytes) -> void* {
        void* p = ws + off;
        off = (off + bytes + 255) & ~(size_t)255;
        return p;
    };
    int*    flags = (int*)alloc(256);
    ushort* xc    = (ushort*)alloc((size_t)N * 256 * 2);
    ushort* bufXW = (ushort*)alloc((size_t)N * 128 * 2);
    ushort* bufH  = (ushort*)alloc((size_t)N * 128 * 2);
    int*    cEi   = (int*)alloc((size_t)2 * E * 4);
    int*    cEp   = (int*)alloc((size_t)2 * Ep * 4);
    int*    cEn   = (int*)alloc((size_t)2 * En * 4);
    float*  dinv  = (float*)alloc((size_t)N * 4);
    int*    deg   = (int*)alloc((size_t)N * 4);
    int*    cur   = (int*)alloc((size_t)N * 4);
    int*    rowp  = (int*)alloc((size_t)(N + 1) * 4);
    int2*   edge  = (int2*)alloc((size_t)E * 8);
    int*    bsum  = (int*)alloc(1024);
    int*    boff  = (int*)alloc(1024);
    ushort* Wt1   = (ushort*)alloc(65536);
    ushort* Wt2   = (ushort*)alloc(32768);
    ushort* WtC   = (ushort*)alloc(4096);
    ushort* b1c   = (ushort*)alloc(256);
    ushort* b2c   = (ushort*)alloc(256);
    ushort* bcc   = (ushort*)alloc(64);
    ushort* Wlc   = (ushort*)alloc(512);
    ushort* blc   = (ushort*)alloc(64);

    hipMemsetAsync(deg, 0, (size_t)N * 4, stream);
    hipMemsetAsync(cur, 0, (size_t)N * 4, stream);

    k_flags<<<1, 64, 0, stream>>>(W1, ei, flags);

    int twoE = 2 * E, twoEp = 2 * Ep, twoEn = 2 * En;
    int idx_total = twoE + twoEp + twoEn;
    k_cvt_idx<<<(idx_total + 255) / 256, 256, 0, stream>>>(ei, eip, ein, cEi, cEp, cEn, deg,
                                                           twoE, twoEp, twoEn, N, flags);
    k_cvt_w<<<203, 256, 0, stream>>>(W1, W2, Wcls, b1, b2, bcls, Wl, bl,
                                     Wt1, Wt2, WtC, b1c, b2c, bcc, Wlc, blc, flags);
    k_cvt_x<<<((N * 256 / 8) + 255) / 256, 256, 0, stream>>>(x, xc, N * 256, flags);

    const int* srcp = cEi;
    const int* dstp = cEi + E;
    int nb = (N + 1023) / 1024;
    k_scan_block<<<nb, 1024, 0, stream>>>(deg, rowp, dinv, bsum, N);
    k_scan_top<<<1, 128, 0, stream>>>(bsum, boff, nb);
    k_scan_add<<<nb, 1024, 0, stream>>>(rowp, boff, N, E);
    k_fill<<<(E + 255) / 256, 256, 0, stream>>>(srcp, dstp, rowp, cur, edge, dinv, E);

    k_gemm<256, true><<<512, 256, 0, stream>>>(x, xc, flags, Wt1, bufXW, N);
    k_conv<<<(N + 3) / 4, 256, 0, stream>>>(bufXW, rowp, edge, dinv, b1c, bufH, N, 1);
    k_gemm<128, false><<<768, 256, 0, stream>>>(bufH, bufH, flags, Wt2, bufXW, N);
    k_conv<<<(N + 3) / 4, 256, 0, stream>>>(bufXW, rowp, edge, dinv, b2c, bufH, N, 0);

    int head_blocks = ((N + 15) / 16 + 3) / 4;
    k_nodehead<<<head_blocks, 256, 0, stream>>>(bufH, WtC, bcc, d_out, N, flags);
    k_link<<<(Ep + En + 3) / 4, 256, 0, stream>>>(bufH, cEp, cEn, Wlc, blc, d_out,
                                                  (size_t)N * 10, Ep, En, flags);
}

// Round 6
// 556.538 us; speedup vs baseline: 1.0812x; 1.0754x over previous
//
#include <hip/hip_runtime.h>
#include <stdint.h>

typedef __attribute__((ext_vector_type(8))) short bf16x8;   // 8 bf16 in 4 VGPRs
typedef __attribute__((ext_vector_type(4))) float f32x4;

__device__ __forceinline__ float b2f(uint32_t h) {
    union { uint32_t u; float f; } v; v.u = h << 16; return v.f;
}
__device__ __forceinline__ ushort f2b(float f) {
    union { float f; uint32_t u; } v; v.f = f;
    uint32_t u = v.u;
    return (ushort)((u + 0x7fffu + ((u >> 16) & 1u)) >> 16);
}
__device__ __forceinline__ float ldin(const void* p, int i, int fp32) {
    return fp32 ? ((const float*)p)[i] : b2f(((const ushort*)p)[i]);
}

// ---------------- dtype sniffer (64 lanes) ----------------
__global__ void k_flags(const void* W1, const void* ei, int* flags) {
    int l = threadIdx.x;
    const ushort* w = (const ushort*)W1;   // W1 ~ U(-1/16,1/16) if true bf16
    float a0 = fabsf(b2f(w[l]));
    float a1 = fabsf(b2f(w[64 + l]));
    bool bad = !(a0 <= 0.25f) || !(a1 <= 0.25f);
    unsigned long long mb = __ballot(bad);
    const int* e = (const int*)ei;         // int64: odd (high) words are 0
    bool z = (l < 16) ? (e[2 * l + 1] == 0) : false;
    unsigned long long mz = __ballot(z);
    if (l == 0) {
        flags[0] = mb ? 1 : 0;                                // fp32 floats?
        flags[1] = (__popcll(mz & 0xffffull) >= 15) ? 1 : 0;  // int64 indices?
    }
}

// ---------------- indices -> clamped int32; dst half also emits degree + rank ----------------
__global__ __launch_bounds__(256) void k_cvt_idx(const void* ei, const void* ep, const void* en,
                                                 int* cEi, int* cEp, int* cEn,
                                                 int* __restrict__ deg, int* __restrict__ rank,
                                                 int twoE, int twoEp, int twoEn, int N,
                                                 const int* __restrict__ flags) {
    int i = blockIdx.x * 256 + threadIdx.x;
    int i64 = flags[1];
    int E = twoE >> 1;
    const void* srcp; int* dstp; int j = i; bool isdst = false;
    if (i < twoE) { srcp = ei; dstp = cEi; isdst = (i >= E); }
    else if (i < twoE + twoEp) { srcp = ep; dstp = cEp; j = i - twoE; }
    else if (i < twoE + twoEp + twoEn) { srcp = en; dstp = cEn; j = i - twoE - twoEp; }
    else return;
    int v = i64 ? (int)((const long long*)srcp)[j] : ((const int*)srcp)[j];
    v = v < 0 ? 0 : (v >= N ? N - 1 : v);
    dstp[j] = v;
    if (isdst) rank[j - E] = atomicAdd(&deg[v], 1);   // rank of edge within its dst bucket
}

// ---------------- weights (transpose) + biases -> bf16 ----------------
__global__ __launch_bounds__(256) void k_cvt_w(const void* W1, const void* W2, const void* Wc,
                                               const void* b1, const void* b2, const void* bc,
                                               const void* Wl, const void* bl,
                                               ushort* Wt1, ushort* Wt2, ushort* WtC,
                                               ushort* b1c, ushort* b2c, ushort* bcc,
                                               ushort* Wlc, ushort* blc,
                                               const int* __restrict__ flags) {
    int i = blockIdx.x * 256 + threadIdx.x;
    int f = flags[0];
    if (i < 32768) {
        int c = i >> 8, k = i & 255;
        Wt1[i] = f2b(ldin(W1, k * 128 + c, f));
    } else if (i < 49152) {
        int j = i - 32768, c = j >> 7, k = j & 127;
        Wt2[j] = f2b(ldin(W2, k * 128 + c, f));
    } else if (i < 51200) {
        int j = i - 49152, c = j >> 7, k = j & 127;
        ushort v = 0;
        if (c < 10) v = f2b(ldin(Wc, k * 10 + c, f));
        WtC[j] = v;
    } else if (i < 51328) {
        int j = i - 51200; b1c[j] = f2b(ldin(b1, j, f));
    } else if (i < 51456) {
        int j = i - 51328; b2c[j] = f2b(ldin(b2, j, f));
    } else if (i < 51472) {
        int j = i - 51456;
        ushort v = 0;
        if (j < 10) v = f2b(ldin(bc, j, f));
        bcc[j] = v;
    } else if (i < 51728) {
        int j = i - 51472; Wlc[j] = f2b(ldin(Wl, j, f));
    } else if (i < 51736) {
        int j = i - 51728;
        ushort v = 0;
        if (j < 1) v = f2b(ldin(bl, 0, f));
        blc[j] = v;
    }
}

// ---------------- x fp32 -> bf16 (streaming, only when fp32) ----------------
__global__ __launch_bounds__(256) void k_cvt_x(const void* __restrict__ x, ushort* __restrict__ xc,
                                               int total, const int* __restrict__ flags) {
    if (!flags[0]) return;
    int i = (blockIdx.x * 256 + threadIdx.x) * 8;
    if (i >= total) return;
    const float* xf = (const float*)x;
    float4 a = *(const float4*)(xf + i);
    float4 b = *(const float4*)(xf + i + 4);
    uint4 o;
    o.x = (uint32_t)f2b(a.x) | ((uint32_t)f2b(a.y) << 16);
    o.y = (uint32_t)f2b(a.z) | ((uint32_t)f2b(a.w) << 16);
    o.z = (uint32_t)f2b(b.x) | ((uint32_t)f2b(b.y) << 16);
    o.w = (uint32_t)f2b(b.z) | ((uint32_t)f2b(b.w) << 16);
    *(uint4*)(xc + i) = o;
}

// ---------------- CSR scan ----------------
__global__ __launch_bounds__(1024) void k_scan_block(const int* __restrict__ deg, int* __restrict__ rowptr,
                                                     float* __restrict__ dinv, int* __restrict__ bsum, int n) {
    __shared__ int sh[1024];
    int t = threadIdx.x;
    int i = blockIdx.x * 1024 + t;
    int val = (i < n) ? deg[i] : 0;
    sh[t] = val; __syncthreads();
    for (int off = 1; off < 1024; off <<= 1) {
        int v = (t >= off) ? sh[t - off] : 0;
        __syncthreads();
        sh[t] += v;
        __syncthreads();
    }
    if (i < n) {
        rowptr[i] = sh[t] - val;
        dinv[i] = rsqrtf((float)(val + 1));
    }
    if (t == 1023) bsum[blockIdx.x] = sh[1023];
}

__global__ __launch_bounds__(128) void k_scan_top(const int* __restrict__ bsum, int* __restrict__ boff, int nb) {
    __shared__ int sh[128];
    int t = threadIdx.x;
    int val = (t < nb) ? bsum[t] : 0;
    sh[t] = val; __syncthreads();
    for (int off = 1; off < 128; off <<= 1) {
        int v = (t >= off) ? sh[t - off] : 0;
        __syncthreads();
        sh[t] += v;
        __syncthreads();
    }
    if (t < nb) boff[t] = sh[t] - val;
}

__global__ __launch_bounds__(1024) void k_scan_add(int* __restrict__ rowptr, const int* __restrict__ boff,
                                                   int n, int E) {
    int i = blockIdx.x * 1024 + threadIdx.x;
    if (i < n) rowptr[i] += boff[blockIdx.x];
    if (i == 0) rowptr[n] = E;
}

// ---------------- CSR fill (atomic-free): p = rowptr[d] + rank[e] ----------------
__global__ __launch_bounds__(256) void k_fill(const int* __restrict__ src, const int* __restrict__ dst,
                                              const int* __restrict__ rowptr, const int* __restrict__ rank,
                                              int2* __restrict__ edge, const float* __restrict__ dinv, int E) {
    int i = blockIdx.x * 256 + threadIdx.x;
    if (i < E) {
        int d = dst[i];
        int s = src[i];
        int p = rowptr[d] + rank[i];
        float w = dinv[s] * dinv[d];
        edge[p] = make_int2(s, __float_as_int(w));
    }
}

// ---------------- MFMA GEMM (bf16 A): Out[N,128] = X[N,K] @ W[K,128] ----------------
// B staged once per block into LDS in fragment order (ds_read_b128 conflict-free).
// 2 M-tiles per wave-iteration: 16 A-loads issue back-to-back -> deep MLP, no spill.
template <int K, bool SEL>
__global__ __launch_bounds__(256, 2) void k_gemm(const void* __restrict__ Xraw,
                                                 const ushort* __restrict__ Xc,
                                                 const int* __restrict__ flags,
                                                 const ushort* __restrict__ Wt,
                                                 ushort* __restrict__ Out, int nrows) {
    constexpr int NS = K / 32;            // K-steps
    __shared__ uint4 sB[NS * 8 * 64];     // K=256: 64 KB, K=128: 32 KB

    const int tid = threadIdx.x;
    for (int it = tid; it < NS * 8 * 64; it += 256) {
        int l = it & 63, fn = it >> 6;
        int s = fn >> 3, n = fn & 7;
        int mr = l & 15, q = l >> 4;
        sB[it] = *(const uint4*)(Wt + (size_t)(n * 16 + mr) * K + s * 32 + q * 8);
    }
    __syncthreads();

    const ushort* Xp = SEL ? (flags[0] ? Xc : (const ushort*)Xraw) : (const ushort*)Xraw;
    const int wave = tid >> 6;
    const int l = tid & 63;
    const int q = l >> 4, mr = l & 15;
    const int gw = blockIdx.x * 4 + wave;
    const int nw = gridDim.x * 4;
    const int ntile = (nrows + 15) >> 4;

    for (int tp = gw; tp * 2 < ntile; tp += nw) {
        const int t0 = tp * 2;
        const bool has1 = (t0 + 1 < ntile);
        const int t1 = has1 ? t0 + 1 : t0;
        const int r0 = min(t0 * 16 + mr, nrows - 1);
        const int r1 = min(t1 * 16 + mr, nrows - 1);

        bf16x8 a0[NS], a1[NS];
        const ushort* x0 = Xp + (size_t)r0 * K + q * 8;
        const ushort* x1 = Xp + (size_t)r1 * K + q * 8;
#pragma unroll
        for (int s = 0; s < NS; ++s) a0[s] = *(const bf16x8*)(x0 + s * 32);
#pragma unroll
        for (int s = 0; s < NS; ++s) a1[s] = *(const bf16x8*)(x1 + s * 32);

        f32x4 acc0[8], acc1[8];
#pragma unroll
        for (int n = 0; n < 8; ++n) {
            acc0[n] = (f32x4){0.f, 0.f, 0.f, 0.f};
            acc1[n] = (f32x4){0.f, 0.f, 0.f, 0.f};
        }
#pragma unroll
        for (int s = 0; s < NS; ++s) {
#pragma unroll
            for (int n = 0; n < 8; ++n) {
                bf16x8 b = __builtin_bit_cast(bf16x8, sB[(s * 8 + n) * 64 + l]);
                acc0[n] = __builtin_amdgcn_mfma_f32_16x16x32_bf16(a0[s], b, acc0[n], 0, 0, 0);
                acc1[n] = __builtin_amdgcn_mfma_f32_16x16x32_bf16(a1[s], b, acc1[n], 0, 0, 0);
            }
        }
        // C/D: col = lane&15, row = q*4 + r
#pragma unroll
        for (int n = 0; n < 8; ++n) {
#pragma unroll
            for (int r = 0; r < 4; ++r) {
                int row0 = t0 * 16 + q * 4 + r;
                if (row0 < nrows) Out[(size_t)row0 * 128 + n * 16 + mr] = f2b(acc0[n][r]);
                if (has1) {
                    int row1 = t1 * 16 + q * 4 + r;
                    if (row1 < nrows) Out[(size_t)row1 * 128 + n * 16 + mr] = f2b(acc1[n][r]);
                }
            }
        }
    }
}

// ---------------- GCN aggregate: one wave per dst node, 8 edges in flight ----------------
__global__ __launch_bounds__(256) void k_conv(const ushort* __restrict__ XW, const int* __restrict__ rowptr,
                                              const int2* __restrict__ edge, const float* __restrict__ dinv,
                                              const ushort* __restrict__ bias, ushort* __restrict__ Hout,
                                              int n, int relu) {
    int wave = threadIdx.x >> 6;
    int v = blockIdx.x * 4 + wave;
    if (v >= n) return;
    int l = threadIdx.x & 63;

    int s0 = rowptr[v], s1 = rowptr[v + 1];
    float dv = dinv[v];
    uint32_t pv = *(const uint32_t*)(XW + (size_t)v * 128 + 2 * l);
    float wself = dv * dv;
    float acc0 = b2f(pv & 0xffffu) * wself;
    float acc1 = b2f(pv >> 16) * wself;

    int i = s0;
    while (i + 8 <= s1) {
        int2 e0[8];
#pragma unroll
        for (int j = 0; j < 8; ++j) e0[j] = edge[i + j];
        uint32_t p[8];
#pragma unroll
        for (int j = 0; j < 8; ++j)
            p[j] = *(const uint32_t*)(XW + (size_t)e0[j].x * 128 + 2 * l);
#pragma unroll
        for (int j = 0; j < 8; ++j) {
            float w = __int_as_float(e0[j].y);
            acc0 += b2f(p[j] & 0xffffu) * w;
            acc1 += b2f(p[j] >> 16) * w;
        }
        i += 8;
    }
    if (i < s1) {   // single predicated batch for the tail (<8)
        int2 e0[8];
#pragma unroll
        for (int j = 0; j < 8; ++j) e0[j] = edge[(i + j < s1) ? (i + j) : s0];
        uint32_t p[8];
#pragma unroll
        for (int j = 0; j < 8; ++j)
            p[j] = *(const uint32_t*)(XW + (size_t)e0[j].x * 128 + 2 * l);
#pragma unroll
        for (int j = 0; j < 8; ++j) {
            float w = (i + j < s1) ? __int_as_float(e0[j].y) : 0.f;
            acc0 += b2f(p[j] & 0xffffu) * w;
            acc1 += b2f(p[j] >> 16) * w;
        }
    }

    uint32_t bb = *(const uint32_t*)(bias + 2 * l);
    acc0 += b2f(bb & 0xffffu);
    acc1 += b2f(bb >> 16);
    if (relu) { acc0 = fmaxf(acc0, 0.f); acc1 = fmaxf(acc1, 0.f); }

    uint32_t o = (uint32_t)f2b(acc0) | ((uint32_t)f2b(acc1) << 16);
    *(uint32_t*)(Hout + (size_t)v * 128 + 2 * l) = o;
}

// ---------------- node head ----------------
__global__ __launch_bounds__(256) void k_nodehead(const ushort* __restrict__ H, const ushort* __restrict__ WtC,
                                                  const ushort* __restrict__ bcc, void* __restrict__ out,
                                                  int n, const int* __restrict__ flags) {
    int wave = threadIdx.x >> 6;
    int gw = blockIdx.x * 4 + wave;
    if (gw * 16 >= n) return;
    int fp32o = flags[0];
    int l = threadIdx.x & 63;
    int q = l >> 4, mr = l & 15;
    int m0 = gw * 16;

    f32x4 acc = (f32x4){0.f, 0.f, 0.f, 0.f};
    const ushort* hrow = H + (size_t)(m0 + mr) * 128 + q * 8;
#pragma unroll
    for (int s = 0; s < 4; ++s) {
        bf16x8 a = *(const bf16x8*)(hrow + s * 32);
#pragma unroll
        for (int j = 0; j < 8; ++j) {
            ushort t = (ushort)a[j];
            if (t & 0x8000u) a[j] = 0;   // relu on bf16
        }
        bf16x8 b = *(const bf16x8*)(WtC + (size_t)mr * 128 + s * 32 + q * 8);
        acc = __builtin_amdgcn_mfma_f32_16x16x32_bf16(a, b, acc, 0, 0, 0);
    }

    float bc = b2f(bcc[mr]);
#pragma unroll
    for (int r = 0; r < 4; ++r) {
        float logit = acc[r] + bc;
        float m = (mr < 10) ? logit : -1e30f;
#pragma unroll
        for (int off = 1; off < 16; off <<= 1) m = fmaxf(m, __shfl_xor(m, off, 16));
        float ex = (mr < 10) ? expf(logit - m) : 0.f;
        float ssum = ex;
#pragma unroll
        for (int off = 1; off < 16; off <<= 1) ssum += __shfl_xor(ssum, off, 16);
        if (mr < 10) {
            float lsm = logit - m - logf(ssum);
            size_t idx = (size_t)(m0 + q * 4 + r) * 10 + mr;
            if (fp32o) ((float*)out)[idx] = lsm;
            else ((ushort*)out)[idx] = f2b(lsm);
        }
    }
}

// ---------------- link head: 4 edges per wave, 16 lanes x dwordx4 per row ----------------
__global__ __launch_bounds__(256) void k_link(const ushort* __restrict__ H, const int* __restrict__ pos,
                                              const int* __restrict__ neg, const ushort* __restrict__ Wlc,
                                              const ushort* __restrict__ blc, void* __restrict__ out,
                                              size_t obase, int Ep, int En, const int* __restrict__ flags) {
    int wave = threadIdx.x >> 6;
    int l = threadIdx.x & 63;
    int g = l >> 4, t = l & 15;
    int e = (blockIdx.x * 4 + wave) * 4 + g;
    if (e >= Ep + En) return;
    int fp32o = flags[0];

    const int* P; int eb, off2;
    if (e < Ep) { P = pos; eb = e; off2 = Ep; }
    else { P = neg; eb = e - Ep; off2 = En; }
    int sI = P[eb], dI = P[off2 + eb];

    bf16x8 hs = *(const bf16x8*)(H + (size_t)sI * 128 + t * 8);
    bf16x8 hd = *(const bf16x8*)(H + (size_t)dI * 128 + t * 8);
    bf16x8 w0 = *(const bf16x8*)(Wlc + t * 8);
    bf16x8 w1 = *(const bf16x8*)(Wlc + 128 + t * 8);

    float acc = 0.f;
#pragma unroll
    for (int j = 0; j < 8; ++j) {
        acc += b2f((ushort)hs[j]) * b2f((ushort)w0[j]);
        acc += b2f((ushort)hd[j]) * b2f((ushort)w1[j]);
    }
#pragma unroll
    for (int off = 1; off < 16; off <<= 1) acc += __shfl_xor(acc, off, 16);
    if (t == 0) {
        float vf = acc + b2f(blc[0]);
        size_t idx = obase + (size_t)e;
        if (fp32o) ((float*)out)[idx] = vf;
        else ((ushort*)out)[idx] = f2b(vf);
    }
}

extern "C" void kernel_launch(void* const* d_in, const int* in_sizes, int n_in,
                              void* d_out, int out_size, void* d_ws, size_t ws_size,
                              hipStream_t stream) {
    const void* x    = d_in[0];
    const void* ei   = d_in[1];
    const void* eip  = d_in[2];
    const void* ein  = d_in[3];
    const void* W1   = d_in[4];
    const void* b1   = d_in[5];
    const void* W2   = d_in[6];
    const void* b2   = d_in[7];
    const void* Wcls = d_in[8];
    const void* bcls = d_in[9];
    const void* Wl   = d_in[10];
    const void* bl   = d_in[11];

    const int N  = in_sizes[0] / 256;
    const int E  = in_sizes[1] / 2;
    const int Ep = in_sizes[2] / 2;
    const int En = in_sizes[3] / 2;

    char* ws = (char*)d_ws;
    size_t off = 0;
    auto alloc = [&](size_t bytes) -> void* {
        void* p = ws + off;
        off = (off + bytes + 255) & ~(size_t)255;
        return p;
    };
    int*    flags = (int*)alloc(256);
    ushort* xc    = (ushort*)alloc((size_t)N * 256 * 2);
    ushort* bufXW = (ushort*)alloc((size_t)N * 128 * 2);
    ushort* bufH  = (ushort*)alloc((size_t)N * 128 * 2);
    int*    cEi   = (int*)alloc((size_t)2 * E * 4);
    int*    cEp   = (int*)alloc((size_t)2 * Ep * 4);
    int*    cEn   = (int*)alloc((size_t)2 * En * 4);
    int*    rank  = (int*)alloc((size_t)E * 4);
    float*  dinv  = (float*)alloc((size_t)N * 4);
    int*    deg   = (int*)alloc((size_t)N * 4);
    int*    rowp  = (int*)alloc((size_t)(N + 1) * 4);
    int2*   edge  = (int2*)alloc((size_t)E * 8);
    int*    bsum  = (int*)alloc(1024);
    int*    boff  = (int*)alloc(1024);
    ushort* Wt1   = (ushort*)alloc(65536);
    ushort* Wt2   = (ushort*)alloc(32768);
    ushort* WtC   = (ushort*)alloc(4096);
    ushort* b1c   = (ushort*)alloc(256);
    ushort* b2c   = (ushort*)alloc(256);
    ushort* bcc   = (ushort*)alloc(64);
    ushort* Wlc   = (ushort*)alloc(512);
    ushort* blc   = (ushort*)alloc(64);

    hipMemsetAsync(deg, 0, (size_t)N * 4, stream);

    k_flags<<<1, 64, 0, stream>>>(W1, ei, flags);

    int twoE = 2 * E, twoEp = 2 * Ep, twoEn = 2 * En;
    int idx_total = twoE + twoEp + twoEn;
    k_cvt_idx<<<(idx_total + 255) / 256, 256, 0, stream>>>(ei, eip, ein, cEi, cEp, cEn,
                                                           deg, rank,
                                                           twoE, twoEp, twoEn, N, flags);
    k_cvt_w<<<203, 256, 0, stream>>>(W1, W2, Wcls, b1, b2, bcls, Wl, bl,
                                     Wt1, Wt2, WtC, b1c, b2c, bcc, Wlc, blc, flags);
    k_cvt_x<<<((N * 256 / 8) + 255) / 256, 256, 0, stream>>>(x, xc, N * 256, flags);

    const int* srcp = cEi;
    const int* dstp = cEi + E;
    int nb = (N + 1023) / 1024;
    k_scan_block<<<nb, 1024, 0, stream>>>(deg, rowp, dinv, bsum, N);
    k_scan_top<<<1, 128, 0, stream>>>(bsum, boff, nb);
    k_scan_add<<<nb, 1024, 0, stream>>>(rowp, boff, N, E);
    k_fill<<<(E + 255) / 256, 256, 0, stream>>>(srcp, dstp, rowp, rank, edge, dinv, E);

    k_gemm<256, true><<<512, 256, 0, stream>>>(x, xc, flags, Wt1, bufXW, N);
    k_conv<<<(N + 3) / 4, 256, 0, stream>>>(bufXW, rowp, edge, dinv, b1c, bufH, N, 1);
    k_gemm<128, false><<<768, 256, 0, stream>>>(bufH, bufH, flags, Wt2, bufXW, N);
    k_conv<<<(N + 3) / 4, 256, 0, stream>>>(bufXW, rowp, edge, dinv, b2c, bufH, N, 0);

    int head_blocks = ((N + 15) / 16 + 3) / 4;
    k_nodehead<<<head_blocks, 256, 0, stream>>>(bufH, WtC, bcc, d_out, N, flags);
    k_link<<<(Ep + En + 3) / 4, 256, 0, stream>>>(bufH, cEp, cEn, Wlc, blc, d_out,
                                                  (size_t)N * 10, Ep, En, flags);
}

// Round 7
// 530.336 us; speedup vs baseline: 1.1346x; 1.0494x over previous
//
#include <hip/hip_runtime.h>
#include <stdint.h>

typedef __attribute__((ext_vector_type(8))) short bf16x8;   // 8 bf16 in 4 VGPRs
typedef __attribute__((ext_vector_type(4))) float f32x4;

__device__ __forceinline__ float b2f(uint32_t h) {
    union { uint32_t u; float f; } v; v.u = h << 16; return v.f;
}
__device__ __forceinline__ ushort f2b(float f) {
    union { float f; uint32_t u; } v; v.f = f;
    uint32_t u = v.u;
    return (ushort)((u + 0x7fffu + ((u >> 16) & 1u)) >> 16);
}
__device__ __forceinline__ float ldin(const void* p, int i, int fp32) {
    return fp32 ? ((const float*)p)[i] : b2f(((const ushort*)p)[i]);
}

// ---------------- dtype sniffer (64 lanes) ----------------
__global__ void k_flags(const void* W1, const void* ei, int* flags) {
    int l = threadIdx.x;
    const ushort* w = (const ushort*)W1;   // W1 ~ U(-1/16,1/16) if true bf16
    float a0 = fabsf(b2f(w[l]));
    float a1 = fabsf(b2f(w[64 + l]));
    bool bad = !(a0 <= 0.25f) || !(a1 <= 0.25f);
    unsigned long long mb = __ballot(bad);
    const int* e = (const int*)ei;         // int64: odd (high) words are 0
    bool z = (l < 16) ? (e[2 * l + 1] == 0) : false;
    unsigned long long mz = __ballot(z);
    if (l == 0) {
        flags[0] = mb ? 1 : 0;                                // fp32 floats?
        flags[1] = (__popcll(mz & 0xffffull) >= 15) ? 1 : 0;  // int64 indices?
    }
}

// ---------------- indices -> clamped int32 (no atomics) ----------------
__global__ __launch_bounds__(256) void k_cvt_idx(const void* ei, const void* ep, const void* en,
                                                 int* cEi, int* cEp, int* cEn,
                                                 int twoE, int twoEp, int twoEn, int N,
                                                 const int* __restrict__ flags) {
    int i = blockIdx.x * 256 + threadIdx.x;
    int i64 = flags[1];
    const void* srcp; int* dstp; int j = i;
    if (i < twoE) { srcp = ei; dstp = cEi; }
    else if (i < twoE + twoEp) { srcp = ep; dstp = cEp; j = i - twoE; }
    else if (i < twoE + twoEp + twoEn) { srcp = en; dstp = cEn; j = i - twoE - twoEp; }
    else return;
    int v = i64 ? (int)((const long long*)srcp)[j] : ((const int*)srcp)[j];
    v = v < 0 ? 0 : (v >= N ? N - 1 : v);
    dstp[j] = v;
}

// ---------------- weights (transpose) + biases -> bf16 ----------------
__global__ __launch_bounds__(256) void k_cvt_w(const void* W1, const void* W2, const void* Wc,
                                               const void* b1, const void* b2, const void* bc,
                                               const void* Wl, const void* bl,
                                               ushort* Wt1, ushort* Wt2, ushort* WtC,
                                               ushort* b1c, ushort* b2c, ushort* bcc,
                                               ushort* Wlc, ushort* blc,
                                               const int* __restrict__ flags) {
    int i = blockIdx.x * 256 + threadIdx.x;
    int f = flags[0];
    if (i < 32768) {
        int c = i >> 8, k = i & 255;
        Wt1[i] = f2b(ldin(W1, k * 128 + c, f));
    } else if (i < 49152) {
        int j = i - 32768, c = j >> 7, k = j & 127;
        Wt2[j] = f2b(ldin(W2, k * 128 + c, f));
    } else if (i < 51200) {
        int j = i - 49152, c = j >> 7, k = j & 127;
        ushort v = 0;
        if (c < 10) v = f2b(ldin(Wc, k * 10 + c, f));
        WtC[j] = v;
    } else if (i < 51328) {
        int j = i - 51200; b1c[j] = f2b(ldin(b1, j, f));
    } else if (i < 51456) {
        int j = i - 51328; b2c[j] = f2b(ldin(b2, j, f));
    } else if (i < 51472) {
        int j = i - 51456;
        ushort v = 0;
        if (j < 10) v = f2b(ldin(bc, j, f));
        bcc[j] = v;
    } else if (i < 51728) {
        int j = i - 51472; Wlc[j] = f2b(ldin(Wl, j, f));
    } else if (i < 51736) {
        int j = i - 51728;
        ushort v = 0;
        if (j < 1) v = f2b(ldin(bl, 0, f));
        blc[j] = v;
    }
}

// ---------------- x fp32 -> bf16 (streaming, only when fp32) ----------------
__global__ __launch_bounds__(256) void k_cvt_x(const void* __restrict__ x, ushort* __restrict__ xc,
                                               int total, const int* __restrict__ flags) {
    if (!flags[0]) return;
    int i = (blockIdx.x * 256 + threadIdx.x) * 8;
    if (i >= total) return;
    const float* xf = (const float*)x;
    float4 a = *(const float4*)(xf + i);
    float4 b = *(const float4*)(xf + i + 4);
    uint4 o;
    o.x = (uint32_t)f2b(a.x) | ((uint32_t)f2b(a.y) << 16);
    o.y = (uint32_t)f2b(a.z) | ((uint32_t)f2b(a.w) << 16);
    o.z = (uint32_t)f2b(b.x) | ((uint32_t)f2b(b.y) << 16);
    o.w = (uint32_t)f2b(b.z) | ((uint32_t)f2b(b.w) << 16);
    *(uint4*)(xc + i) = o;
}

// ---------------- pass 1: coarse histogram (bucket = dst>>8), LDS atomics only ----------------
// Requires N <= 512*256 = 131072.
__global__ __launch_bounds__(256) void k_hist1(const int* __restrict__ dst, int* __restrict__ histM,
                                               int E, int NB1) {
    __shared__ int h[512];
    for (int j = threadIdx.x; j < 512; j += 256) h[j] = 0;
    __syncthreads();
    int base = blockIdx.x * 4096;
    for (int j = threadIdx.x; j < 4096; j += 256) {
        int i = base + j;
        if (i < E) atomicAdd(&h[dst[i] >> 8], 1);
    }
    __syncthreads();
    for (int j = threadIdx.x; j < 512; j += 256)
        histM[j * NB1 + blockIdx.x] = h[j];     // bucket-major for the scan
}

// ---------------- generic exclusive scan (matrix) ----------------
__global__ __launch_bounds__(1024) void k_mscan_block(const int* __restrict__ in, int* __restrict__ out,
                                                      int* __restrict__ bsum, int len) {
    __shared__ int sh[1024];
    int t = threadIdx.x;
    int i = blockIdx.x * 1024 + t;
    int val = (i < len) ? in[i] : 0;
    sh[t] = val; __syncthreads();
    for (int off = 1; off < 1024; off <<= 1) {
        int v = (t >= off) ? sh[t - off] : 0;
        __syncthreads();
        sh[t] += v;
        __syncthreads();
    }
    if (i < len) out[i] = sh[t] - val;
    if (t == 1023) bsum[blockIdx.x] = sh[1023];
}

__global__ __launch_bounds__(1024) void k_mscan_top(int* __restrict__ bsum, int nb) {
    __shared__ int sh[1024];
    int t = threadIdx.x;
    int val = (t < nb) ? bsum[t] : 0;
    sh[t] = val; __syncthreads();
    for (int off = 1; off < 1024; off <<= 1) {
        int v = (t >= off) ? sh[t - off] : 0;
        __syncthreads();
        sh[t] += v;
        __syncthreads();
    }
    if (t < nb) bsum[t] = sh[t] - val;
}

__global__ __launch_bounds__(1024) void k_mscan_add(int* __restrict__ out, const int* __restrict__ bsum, int len) {
    int i = blockIdx.x * 1024 + threadIdx.x;
    if (i < len) out[i] += bsum[blockIdx.x];
}

// coarse-bucket boundaries in the grouped array
__global__ __launch_bounds__(512) void k_cbs(const int* __restrict__ off, int* __restrict__ cbs, int E, int NB1) {
    int t = threadIdx.x;
    cbs[t] = off[t * NB1];
    if (t == 0) cbs[512] = E;
}

// ---------------- pass 1 scatter: group edges by coarse bucket (LDS atomics only) ----------------
__global__ __launch_bounds__(256) void k_scatter1(const int* __restrict__ src, const int* __restrict__ dst,
                                                  const int* __restrict__ off, int2* __restrict__ grouped,
                                                  int E, int NB1) {
    __shared__ int o[512];
    for (int j = threadIdx.x; j < 512; j += 256) o[j] = off[j * NB1 + blockIdx.x];
    __syncthreads();
    int base = blockIdx.x * 4096;
    for (int j = threadIdx.x; j < 4096; j += 256) {
        int i = base + j;
        if (i < E) {
            int d = dst[i];
            int p = atomicAdd(&o[d >> 8], 1);
            grouped[p] = make_int2(src[i], d);
        }
    }
}

// ---------------- pass 2a: exact degrees (one block per coarse bucket, non-atomic global writes) ----------------
__global__ __launch_bounds__(256) void k_deg2(const int2* __restrict__ grouped, const int* __restrict__ cbs,
                                              int* __restrict__ deg, int N) {
    __shared__ int c[256];
    c[threadIdx.x] = 0;
    __syncthreads();
    int b = blockIdx.x;
    int s0 = cbs[b], s1 = cbs[b + 1];
    for (int i = s0 + threadIdx.x; i < s1; i += 256)
        atomicAdd(&c[grouped[i].y & 255], 1);
    __syncthreads();
    int v = b * 256 + threadIdx.x;
    if (v < N) deg[v] = c[threadIdx.x];
}

// ---------------- CSR scan (deg -> rowptr, dinv) ----------------
__global__ __launch_bounds__(1024) void k_scan_block(const int* __restrict__ deg, int* __restrict__ rowptr,
                                                     float* __restrict__ dinv, int* __restrict__ bsum, int n) {
    __shared__ int sh[1024];
    int t = threadIdx.x;
    int i = blockIdx.x * 1024 + t;
    int val = (i < n) ? deg[i] : 0;
    sh[t] = val; __syncthreads();
    for (int off = 1; off < 1024; off <<= 1) {
        int v = (t >= off) ? sh[t - off] : 0;
        __syncthreads();
        sh[t] += v;
        __syncthreads();
    }
    if (i < n) {
        rowptr[i] = sh[t] - val;
        dinv[i] = rsqrtf((float)(val + 1));
    }
    if (t == 1023) bsum[blockIdx.x] = sh[1023];
}

__global__ __launch_bounds__(128) void k_scan_top(const int* __restrict__ bsum, int* __restrict__ boff, int nb) {
    __shared__ int sh[128];
    int t = threadIdx.x;
    int val = (t < nb) ? bsum[t] : 0;
    sh[t] = val; __syncthreads();
    for (int off = 1; off < 128; off <<= 1) {
        int v = (t >= off) ? sh[t - off] : 0;
        __syncthreads();
        sh[t] += v;
        __syncthreads();
    }
    if (t < nb) boff[t] = sh[t] - val;
}

__global__ __launch_bounds__(1024) void k_scan_add(int* __restrict__ rowptr, const int* __restrict__ boff,
                                                   int n, int E) {
    int i = blockIdx.x * 1024 + threadIdx.x;
    if (i < n) rowptr[i] += boff[blockIdx.x];
    if (i == 0) rowptr[n] = E;
}

// ---------------- pass 2b: final CSR fill + weights (LDS atomics only) ----------------
__global__ __launch_bounds__(256) void k_fill2(const int2* __restrict__ grouped, const int* __restrict__ cbs,
                                               const int* __restrict__ rowptr, const float* __restrict__ dinv,
                                               int2* __restrict__ edge, int N) {
    __shared__ int o[256];
    int b = blockIdx.x;
    int v = b * 256 + threadIdx.x;
    o[threadIdx.x] = (v < N) ? rowptr[v] : 0;
    __syncthreads();
    int s0 = cbs[b], s1 = cbs[b + 1];
    for (int i = s0 + threadIdx.x; i < s1; i += 256) {
        int2 e = grouped[i];
        int p = atomicAdd(&o[e.y & 255], 1);
        float w = dinv[e.x] * dinv[e.y];     // dinv[e.y] is L1-hot (256-value window)
        edge[p] = make_int2(e.x, __float_as_int(w));
    }
}

// ---------------- MFMA GEMM (bf16 A): Out[N,128] = X[N,K] @ W[K,128] ----------------
template <int K, bool SEL>
__global__ __launch_bounds__(256, 2) void k_gemm(const void* __restrict__ Xraw,
                                                 const ushort* __restrict__ Xc,
                                                 const int* __restrict__ flags,
                                                 const ushort* __restrict__ Wt,
                                                 ushort* __restrict__ Out, int nrows) {
    constexpr int NS = K / 32;            // K-steps
    __shared__ uint4 sB[NS * 8 * 64];     // K=256: 64 KB, K=128: 32 KB

    const int tid = threadIdx.x;
    for (int it = tid; it < NS * 8 * 64; it += 256) {
        int l = it & 63, fn = it >> 6;
        int s = fn >> 3, n = fn & 7;
        int mr = l & 15, q = l >> 4;
        sB[it] = *(const uint4*)(Wt + (size_t)(n * 16 + mr) * K + s * 32 + q * 8);
    }
    __syncthreads();

    const ushort* Xp = SEL ? (flags[0] ? Xc : (const ushort*)Xraw) : (const ushort*)Xraw;
    const int wave = tid >> 6;
    const int l = tid & 63;
    const int q = l >> 4, mr = l & 15;
    const int gw = blockIdx.x * 4 + wave;
    const int nw = gridDim.x * 4;
    const int ntile = (nrows + 15) >> 4;

    for (int tp = gw; tp * 2 < ntile; tp += nw) {
        const int t0 = tp * 2;
        const bool has1 = (t0 + 1 < ntile);
        const int t1 = has1 ? t0 + 1 : t0;
        const int r0 = min(t0 * 16 + mr, nrows - 1);
        const int r1 = min(t1 * 16 + mr, nrows - 1);

        bf16x8 a0[NS], a1[NS];
        const ushort* x0 = Xp + (size_t)r0 * K + q * 8;
        const ushort* x1 = Xp + (size_t)r1 * K + q * 8;
#pragma unroll
        for (int s = 0; s < NS; ++s) a0[s] = *(const bf16x8*)(x0 + s * 32);
#pragma unroll
        for (int s = 0; s < NS; ++s) a1[s] = *(const bf16x8*)(x1 + s * 32);

        f32x4 acc0[8], acc1[8];
#pragma unroll
        for (int n = 0; n < 8; ++n) {
            acc0[n] = (f32x4){0.f, 0.f, 0.f, 0.f};
            acc1[n] = (f32x4){0.f, 0.f, 0.f, 0.f};
        }
#pragma unroll
        for (int s = 0; s < NS; ++s) {
#pragma unroll
            for (int n = 0; n < 8; ++n) {
                bf16x8 b = __builtin_bit_cast(bf16x8, sB[(s * 8 + n) * 64 + l]);
                acc0[n] = __builtin_amdgcn_mfma_f32_16x16x32_bf16(a0[s], b, acc0[n], 0, 0, 0);
                acc1[n] = __builtin_amdgcn_mfma_f32_16x16x32_bf16(a1[s], b, acc1[n], 0, 0, 0);
            }
        }
        // C/D: col = lane&15, row = q*4 + r
#pragma unroll
        for (int n = 0; n < 8; ++n) {
#pragma unroll
            for (int r = 0; r < 4; ++r) {
                int row0 = t0 * 16 + q * 4 + r;
                if (row0 < nrows) Out[(size_t)row0 * 128 + n * 16 + mr] = f2b(acc0[n][r]);
                if (has1) {
                    int row1 = t1 * 16 + q * 4 + r;
                    if (row1 < nrows) Out[(size_t)row1 * 128 + n * 16 + mr] = f2b(acc1[n][r]);
                }
            }
        }
    }
}

// ---------------- GCN aggregate: one wave per dst node, 8 edges in flight ----------------
__global__ __launch_bounds__(256) void k_conv(const ushort* __restrict__ XW, const int* __restrict__ rowptr,
                                              const int2* __restrict__ edge, const float* __restrict__ dinv,
                                              const ushort* __restrict__ bias, ushort* __restrict__ Hout,
                                              int n, int relu) {
    int wave = threadIdx.x >> 6;
    int v = blockIdx.x * 4 + wave;
    if (v >= n) return;
    int l = threadIdx.x & 63;

    int s0 = rowptr[v], s1 = rowptr[v + 1];
    float dv = dinv[v];
    uint32_t pv = *(const uint32_t*)(XW + (size_t)v * 128 + 2 * l);
    float wself = dv * dv;
    float acc0 = b2f(pv & 0xffffu) * wself;
    float acc1 = b2f(pv >> 16) * wself;

    int i = s0;
    while (i + 8 <= s1) {
        int2 e0[8];
#pragma unroll
        for (int j = 0; j < 8; ++j) e0[j] = edge[i + j];
        uint32_t p[8];
#pragma unroll
        for (int j = 0; j < 8; ++j)
            p[j] = *(const uint32_t*)(XW + (size_t)e0[j].x * 128 + 2 * l);
#pragma unroll
        for (int j = 0; j < 8; ++j) {
            float w = __int_as_float(e0[j].y);
            acc0 += b2f(p[j] & 0xffffu) * w;
            acc1 += b2f(p[j] >> 16) * w;
        }
        i += 8;
    }
    if (i < s1) {   // single predicated batch for the tail (<8)
        int2 e0[8];
#pragma unroll
        for (int j = 0; j < 8; ++j) e0[j] = edge[(i + j < s1) ? (i + j) : s0];
        uint32_t p[8];
#pragma unroll
        for (int j = 0; j < 8; ++j)
            p[j] = *(const uint32_t*)(XW + (size_t)e0[j].x * 128 + 2 * l);
#pragma unroll
        for (int j = 0; j < 8; ++j) {
            float w = (i + j < s1) ? __int_as_float(e0[j].y) : 0.f;
            acc0 += b2f(p[j] & 0xffffu) * w;
            acc1 += b2f(p[j] >> 16) * w;
        }
    }

    uint32_t bb = *(const uint32_t*)(bias + 2 * l);
    acc0 += b2f(bb & 0xffffu);
    acc1 += b2f(bb >> 16);
    if (relu) { acc0 = fmaxf(acc0, 0.f); acc1 = fmaxf(acc1, 0.f); }

    uint32_t o = (uint32_t)f2b(acc0) | ((uint32_t)f2b(acc1) << 16);
    *(uint32_t*)(Hout + (size_t)v * 128 + 2 * l) = o;
}

// ---------------- node head ----------------
__global__ __launch_bounds__(256) void k_nodehead(const ushort* __restrict__ H, const ushort* __restrict__ WtC,
                                                  const ushort* __restrict__ bcc, void* __restrict__ out,
                                                  int n, const int* __restrict__ flags) {
    int wave = threadIdx.x >> 6;
    int gw = blockIdx.x * 4 + wave;
    if (gw * 16 >= n) return;
    int fp32o = flags[0];
    int l = threadIdx.x & 63;
    int q = l >> 4, mr = l & 15;
    int m0 = gw * 16;

    f32x4 acc = (f32x4){0.f, 0.f, 0.f, 0.f};
    const ushort* hrow = H + (size_t)(m0 + mr) * 128 + q * 8;
#pragma unroll
    for (int s = 0; s < 4; ++s) {
        bf16x8 a = *(const bf16x8*)(hrow + s * 32);
#pragma unroll
        for (int j = 0; j < 8; ++j) {
            ushort t = (ushort)a[j];
            if (t & 0x8000u) a[j] = 0;   // relu on bf16
        }
        bf16x8 b = *(const bf16x8*)(WtC + (size_t)mr * 128 + s * 32 + q * 8);
        acc = __builtin_amdgcn_mfma_f32_16x16x32_bf16(a, b, acc, 0, 0, 0);
    }

    float bc = b2f(bcc[mr]);
#pragma unroll
    for (int r = 0; r < 4; ++r) {
        float logit = acc[r] + bc;
        float m = (mr < 10) ? logit : -1e30f;
#pragma unroll
        for (int off = 1; off < 16; off <<= 1) m = fmaxf(m, __shfl_xor(m, off, 16));
        float ex = (mr < 10) ? expf(logit - m) : 0.f;
        float ssum = ex;
#pragma unroll
        for (int off = 1; off < 16; off <<= 1) ssum += __shfl_xor(ssum, off, 16);
        if (mr < 10) {
            float lsm = logit - m - logf(ssum);
            size_t idx = (size_t)(m0 + q * 4 + r) * 10 + mr;
            if (fp32o) ((float*)out)[idx] = lsm;
            else ((ushort*)out)[idx] = f2b(lsm);
        }
    }
}

// ---------------- link head: 4 edges per wave, 16 lanes x dwordx4 per row ----------------
__global__ __launch_bounds__(256) void k_link(const ushort* __restrict__ H, const int* __restrict__ pos,
                                              const int* __restrict__ neg, const ushort* __restrict__ Wlc,
                                              const ushort* __restrict__ blc, void* __restrict__ out,
                                              size_t obase, int Ep, int En, const int* __restrict__ flags) {
    int wave = threadIdx.x >> 6;
    int l = threadIdx.x & 63;
    int g = l >> 4, t = l & 15;
    int e = (blockIdx.x * 4 + wave) * 4 + g;
    if (e >= Ep + En) return;
    int fp32o = flags[0];

    const int* P; int eb, off2;
    if (e < Ep) { P = pos; eb = e; off2 = Ep; }
    else { P = neg; eb = e - Ep; off2 = En; }
    int sI = P[eb], dI = P[off2 + eb];

    bf16x8 hs = *(const bf16x8*)(H + (size_t)sI * 128 + t * 8);
    bf16x8 hd = *(const bf16x8*)(H + (size_t)dI * 128 + t * 8);
    bf16x8 w0 = *(const bf16x8*)(Wlc + t * 8);
    bf16x8 w1 = *(const bf16x8*)(Wlc + 128 + t * 8);

    float acc = 0.f;
#pragma unroll
    for (int j = 0; j < 8; ++j) {
        acc += b2f((ushort)hs[j]) * b2f((ushort)w0[j]);
        acc += b2f((ushort)hd[j]) * b2f((ushort)w1[j]);
    }
#pragma unroll
    for (int off = 1; off < 16; off <<= 1) acc += __shfl_xor(acc, off, 16);
    if (t == 0) {
        float vf = acc + b2f(blc[0]);
        size_t idx = obase + (size_t)e;
        if (fp32o) ((float*)out)[idx] = vf;
        else ((ushort*)out)[idx] = f2b(vf);
    }
}

extern "C" void kernel_launch(void* const* d_in, const int* in_sizes, int n_in,
                              void* d_out, int out_size, void* d_ws, size_t ws_size,
                              hipStream_t stream) {
    const void* x    = d_in[0];
    const void* ei   = d_in[1];
    const void* eip  = d_in[2];
    const void* ein  = d_in[3];
    const void* W1   = d_in[4];
    const void* b1   = d_in[5];
    const void* W2   = d_in[6];
    const void* b2   = d_in[7];
    const void* Wcls = d_in[8];
    const void* bcls = d_in[9];
    const void* Wl   = d_in[10];
    const void* bl   = d_in[11];

    const int N  = in_sizes[0] / 256;
    const int E  = in_sizes[1] / 2;
    const int Ep = in_sizes[2] / 2;
    const int En = in_sizes[3] / 2;

    const int NB1  = (E + 4095) / 4096;
    const int mlen = 512 * NB1;
    const int mb   = (mlen + 1023) / 1024;

    char* ws = (char*)d_ws;
    size_t off = 0;
    auto alloc = [&](size_t bytes) -> void* {
        void* p = ws + off;
        off = (off + bytes + 255) & ~(size_t)255;
        return p;
    };
    int*    flags  = (int*)alloc(256);
    ushort* xc     = (ushort*)alloc((size_t)N * 256 * 2);
    ushort* bufXW  = (ushort*)alloc((size_t)N * 128 * 2);
    ushort* bufH   = (ushort*)alloc((size_t)N * 128 * 2);
    int*    cEi    = (int*)alloc((size_t)2 * E * 4);
    int*    cEp    = (int*)alloc((size_t)2 * Ep * 4);
    int*    cEn    = (int*)alloc((size_t)2 * En * 4);
    int2*   grouped= (int2*)alloc((size_t)E * 8);
    int*    histM  = (int*)alloc((size_t)mlen * 4);
    int*    offM   = (int*)alloc((size_t)mlen * 4);
    int*    msum   = (int*)alloc(4096);
    int*    cbs    = (int*)alloc(513 * 4);
    float*  dinv   = (float*)alloc((size_t)N * 4);
    int*    deg    = (int*)alloc((size_t)N * 4);
    int*    rowp   = (int*)alloc((size_t)(N + 1) * 4);
    int2*   edge   = (int2*)alloc((size_t)E * 8);
    int*    bsum   = (int*)alloc(1024);
    int*    boff   = (int*)alloc(1024);
    ushort* Wt1    = (ushort*)alloc(65536);
    ushort* Wt2    = (ushort*)alloc(32768);
    ushort* WtC    = (ushort*)alloc(4096);
    ushort* b1c    = (ushort*)alloc(256);
    ushort* b2c    = (ushort*)alloc(256);
    ushort* bcc    = (ushort*)alloc(64);
    ushort* Wlc    = (ushort*)alloc(512);
    ushort* blc    = (ushort*)alloc(64);

    k_flags<<<1, 64, 0, stream>>>(W1, ei, flags);

    int twoE = 2 * E, twoEp = 2 * Ep, twoEn = 2 * En;
    int idx_total = twoE + twoEp + twoEn;
    k_cvt_idx<<<(idx_total + 255) / 256, 256, 0, stream>>>(ei, eip, ein, cEi, cEp, cEn,
                                                           twoE, twoEp, twoEn, N, flags);
    k_cvt_w<<<203, 256, 0, stream>>>(W1, W2, Wcls, b1, b2, bcls, Wl, bl,
                                     Wt1, Wt2, WtC, b1c, b2c, bcc, Wlc, blc, flags);
    k_cvt_x<<<((N * 256 / 8) + 255) / 256, 256, 0, stream>>>(x, xc, N * 256, flags);

    const int* srcp = cEi;
    const int* dstp = cEi + E;

    // ---- CSR build: zero global atomics ----
    k_hist1<<<NB1, 256, 0, stream>>>(dstp, histM, E, NB1);
    k_mscan_block<<<mb, 1024, 0, stream>>>(histM, offM, msum, mlen);
    k_mscan_top<<<1, 1024, 0, stream>>>(msum, mb);
    k_mscan_add<<<mb, 1024, 0, stream>>>(offM, msum, mlen);
    k_cbs<<<1, 512, 0, stream>>>(offM, cbs, E, NB1);
    k_scatter1<<<NB1, 256, 0, stream>>>(srcp, dstp, offM, grouped, E, NB1);
    k_deg2<<<512, 256, 0, stream>>>(grouped, cbs, deg, N);
    int nb = (N + 1023) / 1024;
    k_scan_block<<<nb, 1024, 0, stream>>>(deg, rowp, dinv, bsum, N);
    k_scan_top<<<1, 128, 0, stream>>>(bsum, boff, nb);
    k_scan_add<<<nb, 1024, 0, stream>>>(rowp, boff, N, E);
    k_fill2<<<512, 256, 0, stream>>>(grouped, cbs, rowp, dinv, edge, N);

    k_gemm<256, true><<<512, 256, 0, stream>>>(x, xc, flags, Wt1, bufXW, N);
    k_conv<<<(N + 3) / 4, 256, 0, stream>>>(bufXW, rowp, edge, dinv, b1c, bufH, N, 1);
    k_gemm<128, false><<<768, 256, 0, stream>>>(bufH, bufH, flags, Wt2, bufXW, N);
    k_conv<<<(N + 3) / 4, 256, 0, stream>>>(bufXW, rowp, edge, dinv, b2c, bufH, N, 0);

    int head_blocks = ((N + 15) / 16 + 3) / 4;
    k_nodehead<<<head_blocks, 256, 0, stream>>>(bufH, WtC, bcc, d_out, N, flags);
    k_link<<<(Ep + En + 3) / 4, 256, 0, stream>>>(bufH, cEp, cEn, Wlc, blc, d_out,
                                                  (size_t)N * 10, Ep, En, flags);
}